// Round 1
// baseline (189.651 us; speedup 1.0000x reference)
//
#include <hip/hip_runtime.h>
#include <cstdint>

#define BN_EPS 1e-5f

static constexpr int NB = 8192;
static constexpr int JLIN = 500;

typedef int v4i  __attribute__((ext_vector_type(4)));
typedef int v16i __attribute__((ext_vector_type(16)));

// ---------------------------------------------------------------------------
// ws layout
//  h2b    [8192][128] u32      @ 0         4 MB  (bit-packed, row-major/sample)
//  wbfrag [16][128][64] uint4  @ 4194304   2 MB  (lin B frags, lane order)
//  h3w    [8192][16] u32       @ 6291456   512 KB
//  cdat   [640] u32            @ 6815744   (thresholds at [576..639]; masks legacy)
//  lut    [512] u32            @ 6818304
//  wout   [160] u32            @ 6820352
//  Tlin   [512] i32            @ 6820992
//  (gap: Bs legacy)            @ 6823040
//  wcfrag [9][2][64] uint4     @ 6855808   18 KB (conv2 B frags, lane order,
//                                           bytes = sign(w)*chsign, +-1)
// ---------------------------------------------------------------------------

// ---------------------------------------------------------------------------
// pack kernel, grid = 525 blocks:
//  0..511   : wbfrag (lin)     512,513: conv1 LUT    514..519: misc
//  520..524 : wcfrag (conv2 MFMA B fragments)
// ---------------------------------------------------------------------------
__global__ __launch_bounds__(256) void pack_kernel(
    const float* __restrict__ conv1_w, const float* __restrict__ conv1_b,
    const float* __restrict__ conv2_w, const float* __restrict__ conv2_b,
    const float* __restrict__ lin_w, const float* __restrict__ lin_b,
    const float* __restrict__ out_w,
    const float* __restrict__ bn1_g, const float* __restrict__ bn1_b,
    const float* __restrict__ bn1_m, const float* __restrict__ bn1_v,
    const float* __restrict__ bn2_g, const float* __restrict__ bn2_b,
    const float* __restrict__ bn2_m, const float* __restrict__ bn2_v,
    uint4* __restrict__ wbfrag, uint32_t* __restrict__ cdat,
    uint32_t* __restrict__ lut, uint32_t* __restrict__ wout,
    int* __restrict__ Tlin, uint4* __restrict__ wcfrag)
{
    __shared__ float    s_c1w[288];
    __shared__ uint32_t s_wp[32];
    __shared__ float    s_inv1[32], s_sh1[32], s_b1[32];

    int tid = threadIdx.x;
    int b   = blockIdx.x;

    if (b < 512) {
        // ---- lin B fragment: jt, kq, lane; 16 i8 ----
        int e  = b * 256 + tid;
        int L  = e & 63;
        int kq = (e >> 6) & 127;
        int jt = e >> 13;
        int j  = jt * 32 + (L & 31);
        int h  = L >> 5;
        uint32_t dd[4] = {0u, 0u, 0u, 0u};
        if (j < JLIN) {
            int c  = kq >> 1, hi = kq & 1;
            int nb = (hi ? 28 : 32) - 16 * h;
            const float* src = lin_w + (size_t)j * 3840 + c * 60 + hi * 32 + 16 * h;
            #pragma unroll
            for (int i = 0; i < 16; ++i) {
                uint32_t byte = 0;
                if (i < nb) byte = (src[i] > 0.0f) ? 0x01u : 0xFFu;
                dd[i >> 2] |= byte << (8 * (i & 3));
            }
        }
        wbfrag[e] = make_uint4(dd[0], dd[1], dd[2], dd[3]);
        return;
    }

    if (b >= 520) {
        // ---- conv2 B fragment: idx = t*128 + n*64 + L ----
        int e = (b - 520) * 256 + tid;      // 0..1279, use <1152
        if (e < 1152) {
            int t = e >> 7;                 // tap 0..8 (ky*3+kx)
            int n = (e >> 6) & 1;
            int L = e & 63;
            int c = n * 32 + (L & 31);
            int hb = L >> 5;
            bool flip = (bn2_g[c] < 0.0f);  // sign(inv) = sign(gamma)
            uint32_t dd[4] = {0u, 0u, 0u, 0u};
            #pragma unroll
            for (int i = 0; i < 16; ++i) {
                int ic = 16 * hb + i;
                float w = conv2_w[c * 288 + ic * 9 + t];
                uint32_t byte = ((w > 0.0f) == flip) ? 0xFFu : 0x01u;  // -1 / +1
                dd[i >> 2] |= byte << (8 * (i & 3));
            }
            wcfrag[e] = make_uint4(dd[0], dd[1], dd[2], dd[3]);
        }
        return;
    }

    int mb = b - 512;
    if (mb < 2) {
        // ---- conv1 LUT ----
        for (int i = tid; i < 288; i += 256) s_c1w[i] = conv1_w[i];
        __syncthreads();
        if (tid < 32) {
            uint32_t wp = 0;
            for (int t = 0; t < 9; ++t)
                wp |= (s_c1w[tid * 9 + t] < 0.0f ? 1u : 0u) << t;
            s_wp[tid] = wp;
            float inv = bn1_g[tid] / sqrtf(bn1_v[tid] + BN_EPS);
            s_inv1[tid] = inv;
            s_sh1[tid]  = bn1_b[tid] - bn1_m[tid] * inv;
            s_b1[tid]   = conv1_b[tid];
        }
        __syncthreads();
        uint32_t px = (uint32_t)(mb * 256 + tid);
        uint32_t word = 0;
        for (int c = 0; c < 32; ++c) {
            int d = 9 - 2 * __popc(px ^ s_wp[c]);
            float z = __fadd_rn((float)d, s_b1[c]);
            z = __fadd_rn(__fmul_rn(z, s_inv1[c]), s_sh1[c]);
            word |= (z > 0.0f ? 1u : 0u) << c;
        }
        lut[px] = word;
        return;
    }

    int idx = (mb - 2) * 256 + tid;     // 0..1535
    if (idx < 576) {
        // legacy masks (unused by MFMA conv; cheap, kept)
        int c = idx / 9, tap = idx % 9;
        uint32_t w = 0;
        for (int ic = 0; ic < 32; ++ic)
            w |= (conv2_w[c * 288 + ic * 9 + tap] > 0.0f ? 1u : 0u) << ic;
        float inv = bn2_g[c] / sqrtf(bn2_v[c] + BN_EPS);
        if (inv < 0.0f) w = ~w;
        cdat[tap * 64 + c] = w;
    } else if (idx < 576 + 64) {
        // conv2 integer thresholds on D = chsign * conv (exact monotone scan)
        int c = idx - 576;
        float inv = bn2_g[c] / sqrtf(bn2_v[c] + BN_EPS);
        float sh  = bn2_b[c] - bn2_m[c] * inv;
        float b2  = conv2_b[c];
        int T = 10000;
        for (int u = -300; u <= 300; ++u) {
            float v = (inv < 0.0f) ? (float)(-u) : (float)u;
            float z = __fadd_rn(__fmul_rn(__fadd_rn(v, b2), inv), sh);
            if (z > 0.0f) { T = u; break; }
        }
        cdat[576 + c] = (uint32_t)T;
    } else if (idx < 576 + 64 + 512) {
        int j = idx - (576 + 64);
        int T = 10000;
        if (j < JLIN) {
            float lb = lin_b[j];
            int base = (int)floorf(-lb) - 2;
            for (int u = base; u <= base + 5; ++u)
                if (__fadd_rn((float)u, lb) > 0.0f) { T = u; break; }
        }
        Tlin[j] = T;
    } else if (idx < 576 + 64 + 512 + 160) {
        int t = idx - (576 + 64 + 512);
        int j = t >> 4, k = t & 15;
        uint32_t w = 0;
        for (int bb = 0; bb < 32; ++bb) {
            int jj = k * 32 + bb;
            if (jj < JLIN) w |= (out_w[j * 500 + jj] > 0.0f ? 1u : 0u) << bb;
        }
        wout[t] = w;
    }
}

// ---------------------------------------------------------------------------
// conv kernel (MFMA conv2): 2 samples/block, 4096 blocks, wave = (sl, rt).
//  ph1: flat ballot sign-pack (wave -> sample half)
//  ph2: conv1 via LUT, expanded directly to {0,1} bytes in LDS
//  phM: i8 MFMA: rows = 32 positions (tile rt), cols = 64 ch (2 n-tiles),
//       9 accumulating k-steps (taps); A = ds_read_b128 w/ tap-imm offset,
//       B = prebuilt +-1 frags (global, L2-hot). D = chsign*conv directly.
//  epi: threshold -> 32 ballots -> LDS -> per-channel 60-bit word assembly.
// Layout verified on HW by lin2's passing run (same mfma_i32_32x32x32_i8).
// ---------------------------------------------------------------------------
__global__ __launch_bounds__(256) void conv_kernel(
    const float* __restrict__ x,
    const uint32_t* __restrict__ cdat,
    const uint32_t* __restrict__ lut,
    const uint4* __restrict__ wcfrag,
    uint32_t* __restrict__ h2b)
{
    __shared__ __align__(16) uint8_t s_bytes[2 * 286 * 32];   // 18304 B
    __shared__ uint32_t s_lut[512];
    __shared__ __align__(8) uint32_t s_flat[2][44];
    __shared__ uint64_t s_bal[2][2][2][16];                   // [sl][rt][n][r]

    int tid  = threadIdx.x;
    int lane = tid & 63;
    int wv   = tid >> 6;
    int s0   = blockIdx.x * 2;

    s_lut[tid]       = lut[tid];
    s_lut[tid + 256] = lut[tid + 256];

    // ph1: wave (sample = wv>>1, half = wv&1) packs sign bitmap
    {
        int psl = wv >> 1, ph = wv & 1;
        const float* xs = x + (size_t)(s0 + psl) * 1296;
        int it0 = ph * 11, it1 = ph ? 21 : 11;
        for (int it = it0; it < it1; ++it) {
            int f = it * 64 + lane;
            float v = (f < 1296) ? xs[f] : 1.0f;
            uint64_t mk = __ballot(v < 0.0f);
            if (lane == 0) *((uint64_t*)&s_flat[psl][2 * it]) = mk;
        }
    }
    __syncthreads();

    // ph2: conv1 via LUT + expand word -> 32 {0,1} bytes
    for (int i = tid; i < 2 * 286; i += 256) {
        int sl = i / 286, wnd = i - sl * 286;
        int oy = wnd / 26, ox = wnd - oy * 26;
        uint32_t pxb = 0;
        #pragma unroll
        for (int ky = 0; ky < 3; ++ky) {
            int bitpos = 54 * (2 * oy + ky) + 2 * ox;
            int d  = bitpos >> 5;
            int sh = bitpos & 31;
            uint64_t wp = (uint64_t)s_flat[sl][d] | ((uint64_t)s_flat[sl][d + 1] << 32);
            pxb |= (((uint32_t)(wp >> sh)) & 7u) << (3 * ky);
        }
        uint32_t w = s_lut[pxb];
        uint32_t dw[8];
        #pragma unroll
        for (int q = 0; q < 8; ++q)
            dw[q] = (((w >> (4 * q)) & 0xFu) * 0x204081u) & 0x01010101u;
        uint4* dst = (uint4*)(s_bytes + ((size_t)sl * 286 + wnd) * 32);
        dst[0] = make_uint4(dw[0], dw[1], dw[2], dw[3]);
        dst[1] = make_uint4(dw[4], dw[5], dw[6], dw[7]);
    }
    __syncthreads();

    // phM: wave = (sl = wv>>1, rt = wv&1)
    {
        int sl = wv >> 1, rt = wv & 1;
        int p = rt * 32 + (lane & 31);
        if (p > 59) p = 59;                       // pad rows read valid mem
        int oy = p / 12, ox = p - 12 * oy;
        int hb = lane >> 5;
        const uint8_t* abase = s_bytes + ((size_t)sl * 286 + 52 * oy + 2 * ox) * 32 + 16 * hb;
        const uint4* bbase = wcfrag + lane;

        v16i acc0 = {};
        v16i acc1 = {};
        #pragma unroll
        for (int t = 0; t < 9; ++t) {
            const int koff = (t / 3) * 26 + (t % 3);          // ky*26+kx
            uint4 av = *(const uint4*)(abase + koff * 32);
            v4i af = {(int)av.x, (int)av.y, (int)av.z, (int)av.w};
            uint4 b0 = bbase[t * 128];
            uint4 b1 = bbase[t * 128 + 64];
            v4i bf0 = {(int)b0.x, (int)b0.y, (int)b0.z, (int)b0.w};
            v4i bf1 = {(int)b1.x, (int)b1.y, (int)b1.z, (int)b1.w};
            acc0 = __builtin_amdgcn_mfma_i32_32x32x32_i8(af, bf0, acc0, 0, 0, 0);
            acc1 = __builtin_amdgcn_mfma_i32_32x32x32_i8(af, bf1, acc1, 0, 0, 0);
        }

        int T0 = (int)cdat[576 + (lane & 31)];
        int T1 = (int)cdat[576 + 32 + (lane & 31)];
        #pragma unroll
        for (int r = 0; r < 16; ++r) {
            uint64_t m0 = __ballot(acc0[r] >= T0);
            uint64_t m1 = __ballot(acc1[r] >= T1);
            if (lane == 0) {
                s_bal[sl][rt][0][r] = m0;
                s_bal[sl][rt][1][r] = m1;
            }
        }
    }
    __syncthreads();

    // epi: thread (sl, c) assembles the channel's 60-bit word
    if (tid < 128) {
        int esl = tid >> 6, c = tid & 63;
        int n = c >> 5, cc = c & 31;
        uint32_t w0 = 0, w1 = 0;
        #pragma unroll 4
        for (int p = 0; p < 60; ++p) {
            int rt = p >> 5, row = p & 31;
            int hh = (row >> 2) & 1;
            int r  = (row & 3) | ((row >> 3) << 2);
            uint32_t bit = (uint32_t)((s_bal[esl][rt][n][r] >> (cc + 32 * hh)) & 1u);
            if (p < 32) w0 |= bit << p; else w1 |= bit << (p - 32);
        }
        *(uint2*)(h2b + (size_t)(s0 + esl) * 128 + 2 * c) = make_uint2(w0, w1);
    }
}

// ---------------------------------------------------------------------------
// lin2: i8 MFMA GEMM (unchanged from R10, HW-verified).
// ---------------------------------------------------------------------------
__global__ __launch_bounds__(256) void lin2_kernel(
    const uint32_t* __restrict__ h2b,
    const uint4* __restrict__ wbfrag,
    const int* __restrict__ Tlin,
    uint32_t* __restrict__ h3w)
{
    __shared__ uint8_t As[64 * 520];     // 33,280 B

    int tid  = threadIdx.x;
    int lane = tid & 63;
    int wv   = __builtin_amdgcn_readfirstlane((int)(tid >> 6));
    int sblk = blockIdx.x >> 2;
    int jgrp = blockIdx.x & 3;
    int jt   = jgrp * 4 + wv;
    int s0   = sblk * 64;

    int T = Tlin[jt * 32 + (lane & 31)];
    int row  = lane & 31;
    int half = lane >> 5;

    v16i acc0 = {};
    v16i acc1 = {};

    for (int chunk = 0; chunk < 8; ++chunk) {
        for (int e = tid; e < 1024; e += 256) {
            int sm = e >> 4, wl = e & 15;
            uint32_t w = h2b[(size_t)(s0 + sm) * 128 + chunk * 16 + wl];
            uint32_t dw[8];
            #pragma unroll
            for (int q = 0; q < 8; ++q)
                dw[q] = (((w >> (4 * q)) & 0xFu) * 0x204081u) & 0x01010101u;
            uint64_t* dst = (uint64_t*)(As + sm * 520 + wl * 32);
            dst[0] = (uint64_t)dw[0] | ((uint64_t)dw[1] << 32);
            dst[1] = (uint64_t)dw[2] | ((uint64_t)dw[3] << 32);
            dst[2] = (uint64_t)dw[4] | ((uint64_t)dw[5] << 32);
            dst[3] = (uint64_t)dw[6] | ((uint64_t)dw[7] << 32);
        }
        __syncthreads();

        const uint4* bsrc = wbfrag + ((size_t)jt * 128 + chunk * 16) * 64 + lane;
        #pragma unroll 4
        for (int kq = 0; kq < 16; ++kq) {
            uint4 bw = bsrc[kq * 64];
            v4i bf = {(int)bw.x, (int)bw.y, (int)bw.z, (int)bw.w};
            const uint8_t* ap = As + row * 520 + kq * 32 + half * 16;
            uint64_t lo0 = *(const uint64_t*)ap;
            uint64_t hi0 = *(const uint64_t*)(ap + 8);
            const uint8_t* aq = ap + 32 * 520;
            uint64_t lo1 = *(const uint64_t*)aq;
            uint64_t hi1 = *(const uint64_t*)(aq + 8);
            v4i a0 = {(int)(uint32_t)lo0, (int)(lo0 >> 32),
                      (int)(uint32_t)hi0, (int)(hi0 >> 32)};
            v4i a1 = {(int)(uint32_t)lo1, (int)(lo1 >> 32),
                      (int)(uint32_t)hi1, (int)(hi1 >> 32)};
            acc0 = __builtin_amdgcn_mfma_i32_32x32x32_i8(a0, bf, acc0, 0, 0, 0);
            acc1 = __builtin_amdgcn_mfma_i32_32x32x32_i8(a1, bf, acc1, 0, 0, 0);
        }
        __syncthreads();
    }

    #pragma unroll
    for (int r = 0; r < 16; ++r) {
        int row0 = (r & 3) + 8 * (r >> 2);
        uint64_t mk0 = __ballot(acc0[r] >= T);
        uint64_t mk1 = __ballot(acc1[r] >= T);
        if (lane == 0) {
            h3w[(size_t)(s0 + row0) * 16 + jt]          = (uint32_t)mk0;
            h3w[(size_t)(s0 + row0 + 4) * 16 + jt]      = (uint32_t)(mk0 >> 32);
            h3w[(size_t)(s0 + 32 + row0) * 16 + jt]     = (uint32_t)mk1;
            h3w[(size_t)(s0 + 32 + row0 + 4) * 16 + jt] = (uint32_t)(mk1 >> 32);
        }
    }
}

// ---------------------------------------------------------------------------
// out kernel (unchanged from R10)
// ---------------------------------------------------------------------------
__global__ __launch_bounds__(256) void out_kernel(
    const uint32_t* __restrict__ h3w,
    const uint32_t* __restrict__ wout,
    const float* __restrict__ out_b,
    float* __restrict__ out)
{
    int s = blockIdx.x * 256 + threadIdx.x;
    const uint4* hp = (const uint4*)(h3w + (size_t)s * 16);
    uint4 q0 = hp[0], q1 = hp[1], q2 = hp[2], q3 = hp[3];
    uint32_t w[16] = {q0.x, q0.y, q0.z, q0.w, q1.x, q1.y, q1.z, q1.w,
                      q2.x, q2.y, q2.z, q2.w, q3.x, q3.y, q3.z, q3.w};
    int B = 0;
    #pragma unroll
    for (int k = 0; k < 16; ++k) B += __popc(w[k]);
    #pragma unroll
    for (int o = 0; o < 10; ++o) {
        int P = 0;
        #pragma unroll
        for (int k = 0; k < 16; ++k) P += __popc(w[k] & wout[o * 16 + k]);
        out[(size_t)s * 10 + o] = __fadd_rn((float)(2 * P - B), out_b[o]);
    }
}

// ---------------------------------------------------------------------------
extern "C" void kernel_launch(void* const* d_in, const int* in_sizes, int n_in,
                              void* d_out, int out_size, void* d_ws, size_t ws_size,
                              hipStream_t stream)
{
    const float* x       = (const float*)d_in[0];
    const float* conv1_w = (const float*)d_in[1];
    const float* conv1_b = (const float*)d_in[2];
    const float* bn1_g   = (const float*)d_in[3];
    const float* bn1_b   = (const float*)d_in[4];
    const float* bn1_m   = (const float*)d_in[5];
    const float* bn1_v   = (const float*)d_in[6];
    const float* conv2_w = (const float*)d_in[7];
    const float* conv2_b = (const float*)d_in[8];
    const float* bn2_g   = (const float*)d_in[9];
    const float* bn2_b   = (const float*)d_in[10];
    const float* bn2_m   = (const float*)d_in[11];
    const float* bn2_v   = (const float*)d_in[12];
    const float* lin_w   = (const float*)d_in[13];
    const float* lin_b   = (const float*)d_in[14];
    const float* out_w   = (const float*)d_in[15];
    const float* out_b   = (const float*)d_in[16];

    char* ws = (char*)d_ws;
    uint32_t* h2b    = (uint32_t*)(ws + 0);
    uint4*    wbfrag = (uint4*)   (ws + 4194304);
    uint32_t* h3w    = (uint32_t*)(ws + 6291456);
    uint32_t* cdat   = (uint32_t*)(ws + 6815744);
    uint32_t* lut    = (uint32_t*)(ws + 6818304);
    uint32_t* wout   = (uint32_t*)(ws + 6820352);
    int*      Tlin   = (int*)     (ws + 6820992);
    uint4*    wcfrag = (uint4*)   (ws + 6855808);

    pack_kernel<<<525, 256, 0, stream>>>(conv1_w, conv1_b, conv2_w, conv2_b,
                                         lin_w, lin_b, out_w,
                                         bn1_g, bn1_b, bn1_m, bn1_v,
                                         bn2_g, bn2_b, bn2_m, bn2_v,
                                         wbfrag, cdat, lut, wout, Tlin, wcfrag);
    conv_kernel<<<NB / 2, 256, 0, stream>>>(x, cdat, lut, wcfrag, h2b);
    lin2_kernel<<<512, 256, 0, stream>>>(h2b, wbfrag, Tlin, h3w);
    out_kernel<<<32, 256, 0, stream>>>(h3w, wout, out_b, (float*)d_out);
}

// Round 2
// 175.297 us; speedup vs baseline: 1.0819x; 1.0819x over previous
//
#include <hip/hip_runtime.h>
#include <cstdint>

#define BN_EPS 1e-5f

static constexpr int NB = 8192;
static constexpr int JLIN = 500;

typedef int v4i  __attribute__((ext_vector_type(4)));
typedef int v16i __attribute__((ext_vector_type(16)));

// ---------------------------------------------------------------------------
// ws layout
//  h2b    [8192][128] u32      @ 0         4 MB  (bit-packed, row-major/sample)
//  wbfrag [16][128][64] uint4  @ 4194304   2 MB  (lin B frags, lane order)
//  h3w    [8192][16] u32       @ 6291456   512 KB
//  cdat   [640] u32            @ 6815744   (thresholds at [576..639]; masks legacy)
//  lut    [512] u32            @ 6818304
//  wout   [160] u32            @ 6820352
//  Tlin   [512] i32            @ 6820992
//  (gap: Bs legacy)            @ 6823040
//  wcfrag [9][2][64] uint4     @ 6855808   18 KB (conv2 B frags, lane order,
//                                           bytes = sign(w)*chsign, +-1)
// ---------------------------------------------------------------------------

// ---------------------------------------------------------------------------
// pack kernel, grid = 525 blocks (unchanged)
// ---------------------------------------------------------------------------
__global__ __launch_bounds__(256) void pack_kernel(
    const float* __restrict__ conv1_w, const float* __restrict__ conv1_b,
    const float* __restrict__ conv2_w, const float* __restrict__ conv2_b,
    const float* __restrict__ lin_w, const float* __restrict__ lin_b,
    const float* __restrict__ out_w,
    const float* __restrict__ bn1_g, const float* __restrict__ bn1_b,
    const float* __restrict__ bn1_m, const float* __restrict__ bn1_v,
    const float* __restrict__ bn2_g, const float* __restrict__ bn2_b,
    const float* __restrict__ bn2_m, const float* __restrict__ bn2_v,
    uint4* __restrict__ wbfrag, uint32_t* __restrict__ cdat,
    uint32_t* __restrict__ lut, uint32_t* __restrict__ wout,
    int* __restrict__ Tlin, uint4* __restrict__ wcfrag)
{
    __shared__ float    s_c1w[288];
    __shared__ uint32_t s_wp[32];
    __shared__ float    s_inv1[32], s_sh1[32], s_b1[32];

    int tid = threadIdx.x;
    int b   = blockIdx.x;

    if (b < 512) {
        // ---- lin B fragment: jt, kq, lane; 16 i8 ----
        int e  = b * 256 + tid;
        int L  = e & 63;
        int kq = (e >> 6) & 127;
        int jt = e >> 13;
        int j  = jt * 32 + (L & 31);
        int h  = L >> 5;
        uint32_t dd[4] = {0u, 0u, 0u, 0u};
        if (j < JLIN) {
            int c  = kq >> 1, hi = kq & 1;
            int nb = (hi ? 28 : 32) - 16 * h;
            const float* src = lin_w + (size_t)j * 3840 + c * 60 + hi * 32 + 16 * h;
            #pragma unroll
            for (int i = 0; i < 16; ++i) {
                uint32_t byte = 0;
                if (i < nb) byte = (src[i] > 0.0f) ? 0x01u : 0xFFu;
                dd[i >> 2] |= byte << (8 * (i & 3));
            }
        }
        wbfrag[e] = make_uint4(dd[0], dd[1], dd[2], dd[3]);
        return;
    }

    if (b >= 520) {
        // ---- conv2 B fragment: idx = t*128 + n*64 + L ----
        int e = (b - 520) * 256 + tid;      // 0..1279, use <1152
        if (e < 1152) {
            int t = e >> 7;                 // tap 0..8 (ky*3+kx)
            int n = (e >> 6) & 1;
            int L = e & 63;
            int c = n * 32 + (L & 31);
            int hb = L >> 5;
            bool flip = (bn2_g[c] < 0.0f);  // sign(inv) = sign(gamma)
            uint32_t dd[4] = {0u, 0u, 0u, 0u};
            #pragma unroll
            for (int i = 0; i < 16; ++i) {
                int ic = 16 * hb + i;
                float w = conv2_w[c * 288 + ic * 9 + t];
                uint32_t byte = ((w > 0.0f) == flip) ? 0xFFu : 0x01u;  // -1 / +1
                dd[i >> 2] |= byte << (8 * (i & 3));
            }
            wcfrag[e] = make_uint4(dd[0], dd[1], dd[2], dd[3]);
        }
        return;
    }

    int mb = b - 512;
    if (mb < 2) {
        // ---- conv1 LUT ----
        for (int i = tid; i < 288; i += 256) s_c1w[i] = conv1_w[i];
        __syncthreads();
        if (tid < 32) {
            uint32_t wp = 0;
            for (int t = 0; t < 9; ++t)
                wp |= (s_c1w[tid * 9 + t] < 0.0f ? 1u : 0u) << t;
            s_wp[tid] = wp;
            float inv = bn1_g[tid] / sqrtf(bn1_v[tid] + BN_EPS);
            s_inv1[tid] = inv;
            s_sh1[tid]  = bn1_b[tid] - bn1_m[tid] * inv;
            s_b1[tid]   = conv1_b[tid];
        }
        __syncthreads();
        uint32_t px = (uint32_t)(mb * 256 + tid);
        uint32_t word = 0;
        for (int c = 0; c < 32; ++c) {
            int d = 9 - 2 * __popc(px ^ s_wp[c]);
            float z = __fadd_rn((float)d, s_b1[c]);
            z = __fadd_rn(__fmul_rn(z, s_inv1[c]), s_sh1[c]);
            word |= (z > 0.0f ? 1u : 0u) << c;
        }
        lut[px] = word;
        return;
    }

    int idx = (mb - 2) * 256 + tid;     // 0..1535
    if (idx < 576) {
        // legacy masks (unused by MFMA conv; cheap, kept)
        int c = idx / 9, tap = idx % 9;
        uint32_t w = 0;
        for (int ic = 0; ic < 32; ++ic)
            w |= (conv2_w[c * 288 + ic * 9 + tap] > 0.0f ? 1u : 0u) << ic;
        float inv = bn2_g[c] / sqrtf(bn2_v[c] + BN_EPS);
        if (inv < 0.0f) w = ~w;
        cdat[tap * 64 + c] = w;
    } else if (idx < 576 + 64) {
        // conv2 integer thresholds on D = chsign * conv (exact monotone scan)
        int c = idx - 576;
        float inv = bn2_g[c] / sqrtf(bn2_v[c] + BN_EPS);
        float sh  = bn2_b[c] - bn2_m[c] * inv;
        float b2  = conv2_b[c];
        int T = 10000;
        for (int u = -300; u <= 300; ++u) {
            float v = (inv < 0.0f) ? (float)(-u) : (float)u;
            float z = __fadd_rn(__fmul_rn(__fadd_rn(v, b2), inv), sh);
            if (z > 0.0f) { T = u; break; }
        }
        cdat[576 + c] = (uint32_t)T;
    } else if (idx < 576 + 64 + 512) {
        int j = idx - (576 + 64);
        int T = 10000;
        if (j < JLIN) {
            float lb = lin_b[j];
            int base = (int)floorf(-lb) - 2;
            for (int u = base; u <= base + 5; ++u)
                if (__fadd_rn((float)u, lb) > 0.0f) { T = u; break; }
        }
        Tlin[j] = T;
    } else if (idx < 576 + 64 + 512 + 160) {
        int t = idx - (576 + 64 + 512);
        int j = t >> 4, k = t & 15;
        uint32_t w = 0;
        for (int bb = 0; bb < 32; ++bb) {
            int jj = k * 32 + bb;
            if (jj < JLIN) w |= (out_w[j * 500 + jj] > 0.0f ? 1u : 0u) << bb;
        }
        wout[t] = w;
    }
}

// ---------------------------------------------------------------------------
// conv kernel (rewritten): ONE WAVE = ONE SAMPLE, no inter-wave deps.
//  4 samples / 256-thread block, grid = 2048. Single __syncthreads (s_lut).
//  Per wave:
//   ph1: 21 coalesced x loads -> 21 ballots -> per-wave LDS bitmap (u32[44])
//   ph2: 286 conv1 LUT words -> per-wave LDS (stride-1 writes, conflict-free)
//   phM: t-outer loop: load B frags (L2-hot) once per tap; rt-inner expands
//        the window word to {0,1} bytes IN REGISTERS (nibble*0x204081) and
//        issues 4 MFMAs (2 row-tiles x 2 ch-tiles). No big LDS staging.
//   epi: 64 ballots -> per-wave LDS -> all 64 lanes assemble channel words.
//  Wave-internal LDS RAW ordered by s_waitcnt lgkmcnt(0) (no barriers).
// ---------------------------------------------------------------------------
__global__ __launch_bounds__(256) void conv_kernel(
    const float* __restrict__ x,
    const uint32_t* __restrict__ cdat,
    const uint32_t* __restrict__ lut,
    const uint4* __restrict__ wcfrag,
    uint32_t* __restrict__ h2b)
{
    __shared__ uint32_t s_lut[512];
    __shared__ __align__(8) uint32_t s_flat[4][44];   // per-wave sign bitmap
    __shared__ uint32_t s_words[4][288];              // per-wave conv1 words
    __shared__ uint64_t s_bal[4][2][2][16];           // per-wave ballots

    int tid  = threadIdx.x;
    int lane = tid & 63;
    int wv   = tid >> 6;
    int s    = blockIdx.x * 4 + wv;

    s_lut[tid]       = lut[tid];
    s_lut[tid + 256] = lut[tid + 256];
    __syncthreads();

    // ---- ph1: sign bitmap ----
    const float* xs = x + (size_t)s * 1296;
    float xv[21];
    #pragma unroll
    for (int it = 0; it < 21; ++it) {
        int f = it * 64 + lane;
        xv[it] = (f < 1296) ? xs[f] : 1.0f;
    }
    #pragma unroll
    for (int it = 0; it < 21; ++it) {
        uint64_t mk = __ballot(xv[it] < 0.0f);
        if (lane == 0) *(uint64_t*)&s_flat[wv][2 * it] = mk;
    }
    asm volatile("s_waitcnt lgkmcnt(0)" ::: "memory");
    __builtin_amdgcn_sched_barrier(0);

    // ---- ph2: conv1 via LUT -> per-wave word table ----
    #pragma unroll
    for (int ii = 0; ii < 5; ++ii) {
        int wnd = ii * 64 + lane;
        if (wnd < 286) {
            int oy = wnd / 26, ox = wnd - 26 * oy;
            uint32_t pxb = 0;
            #pragma unroll
            for (int ky = 0; ky < 3; ++ky) {
                int bitpos = 54 * (2 * oy + ky) + 2 * ox;
                int d = bitpos >> 5, sh = bitpos & 31;
                uint64_t wp = (uint64_t)s_flat[wv][d] |
                              ((uint64_t)s_flat[wv][d + 1] << 32);
                pxb |= (((uint32_t)(wp >> sh)) & 7u) << (3 * ky);
            }
            s_words[wv][wnd] = s_lut[pxb];
        }
    }
    asm volatile("s_waitcnt lgkmcnt(0)" ::: "memory");
    __builtin_amdgcn_sched_barrier(0);

    // ---- phM: 2 row-tiles x 2 ch-tiles, 9 accumulating taps ----
    int row32 = lane & 31;
    int hb    = lane >> 5;
    int sh_hb = 16 * hb;
    int p1v   = 32 + row32; if (p1v > 59) p1v = 59;
    int wb0, wb1;
    { int oy = row32 / 12, ox = row32 - 12 * oy; wb0 = 52 * oy + 2 * ox; }
    { int oy = p1v / 12,   ox = p1v - 12 * oy;   wb1 = 52 * oy + 2 * ox; }

    v16i acc[2][2] = {};
    #pragma unroll
    for (int t = 0; t < 9; ++t) {
        const int koff = (t / 3) * 26 + (t % 3);
        uint4 b0 = wcfrag[t * 128 + lane];
        uint4 b1 = wcfrag[t * 128 + 64 + lane];
        v4i bf0 = {(int)b0.x, (int)b0.y, (int)b0.z, (int)b0.w};
        v4i bf1 = {(int)b1.x, (int)b1.y, (int)b1.z, (int)b1.w};
        #pragma unroll
        for (int rt = 0; rt < 2; ++rt) {
            uint32_t w  = s_words[wv][(rt ? wb1 : wb0) + koff];
            uint32_t hw = w >> sh_hb;
            v4i af;
            af[0] = (int)((((hw      ) & 0xFu) * 0x204081u) & 0x01010101u);
            af[1] = (int)((((hw >> 4 ) & 0xFu) * 0x204081u) & 0x01010101u);
            af[2] = (int)((((hw >> 8 ) & 0xFu) * 0x204081u) & 0x01010101u);
            af[3] = (int)((((hw >> 12) & 0xFu) * 0x204081u) & 0x01010101u);
            acc[rt][0] = __builtin_amdgcn_mfma_i32_32x32x32_i8(af, bf0, acc[rt][0], 0, 0, 0);
            acc[rt][1] = __builtin_amdgcn_mfma_i32_32x32x32_i8(af, bf1, acc[rt][1], 0, 0, 0);
        }
    }

    // ---- ballots: threshold per channel, write per-wave transpose buffer ----
    int T0 = (int)cdat[576 + row32];
    int T1 = (int)cdat[576 + 32 + row32];
    #pragma unroll
    for (int rt = 0; rt < 2; ++rt) {
        #pragma unroll
        for (int r = 0; r < 16; ++r) {
            uint64_t m0 = __ballot(acc[rt][0][r] >= T0);
            uint64_t m1 = __ballot(acc[rt][1][r] >= T1);
            if (lane == 0) {
                s_bal[wv][rt][0][r] = m0;
                s_bal[wv][rt][1][r] = m1;
            }
        }
    }
    asm volatile("s_waitcnt lgkmcnt(0)" ::: "memory");
    __builtin_amdgcn_sched_barrier(0);

    // ---- epi: each lane = one channel, assemble 60-bit word ----
    {
        int n  = lane >> 5, cc = lane & 31;
        uint32_t w0 = 0, w1 = 0;
        #pragma unroll
        for (int rt = 0; rt < 2; ++rt) {
            #pragma unroll
            for (int r = 0; r < 16; ++r) {
                const int base = (r & 3) + 8 * (r >> 2);      // 0..27
                uint64_t m = s_bal[wv][rt][n][r];
                uint32_t b0 = (uint32_t)(m >> cc) & 1u;
                uint32_t b1 = (uint32_t)(m >> (cc + 32)) & 1u;
                const int p0 = rt * 32 + base;
                const int p1 = p0 + 4;
                if (p0 < 32) w0 |= b0 << p0; else w1 |= b0 << (p0 - 32);
                if (p1 < 60) {
                    if (p1 < 32) w0 |= b1 << p1; else w1 |= b1 << (p1 - 32);
                }
            }
        }
        *(uint2*)(h2b + (size_t)s * 128 + 2 * lane) = make_uint2(w0, w1);
    }
}

// ---------------------------------------------------------------------------
// lin2: i8 MFMA GEMM (unchanged, HW-verified).
// ---------------------------------------------------------------------------
__global__ __launch_bounds__(256) void lin2_kernel(
    const uint32_t* __restrict__ h2b,
    const uint4* __restrict__ wbfrag,
    const int* __restrict__ Tlin,
    uint32_t* __restrict__ h3w)
{
    __shared__ uint8_t As[64 * 520];     // 33,280 B

    int tid  = threadIdx.x;
    int lane = tid & 63;
    int wv   = __builtin_amdgcn_readfirstlane((int)(tid >> 6));
    int sblk = blockIdx.x >> 2;
    int jgrp = blockIdx.x & 3;
    int jt   = jgrp * 4 + wv;
    int s0   = sblk * 64;

    int T = Tlin[jt * 32 + (lane & 31)];
    int row  = lane & 31;
    int half = lane >> 5;

    v16i acc0 = {};
    v16i acc1 = {};

    for (int chunk = 0; chunk < 8; ++chunk) {
        for (int e = tid; e < 1024; e += 256) {
            int sm = e >> 4, wl = e & 15;
            uint32_t w = h2b[(size_t)(s0 + sm) * 128 + chunk * 16 + wl];
            uint32_t dw[8];
            #pragma unroll
            for (int q = 0; q < 8; ++q)
                dw[q] = (((w >> (4 * q)) & 0xFu) * 0x204081u) & 0x01010101u;
            uint64_t* dst = (uint64_t*)(As + sm * 520 + wl * 32);
            dst[0] = (uint64_t)dw[0] | ((uint64_t)dw[1] << 32);
            dst[1] = (uint64_t)dw[2] | ((uint64_t)dw[3] << 32);
            dst[2] = (uint64_t)dw[4] | ((uint64_t)dw[5] << 32);
            dst[3] = (uint64_t)dw[6] | ((uint64_t)dw[7] << 32);
        }
        __syncthreads();

        const uint4* bsrc = wbfrag + ((size_t)jt * 128 + chunk * 16) * 64 + lane;
        #pragma unroll 4
        for (int kq = 0; kq < 16; ++kq) {
            uint4 bw = bsrc[kq * 64];
            v4i bf = {(int)bw.x, (int)bw.y, (int)bw.z, (int)bw.w};
            const uint8_t* ap = As + row * 520 + kq * 32 + half * 16;
            uint64_t lo0 = *(const uint64_t*)ap;
            uint64_t hi0 = *(const uint64_t*)(ap + 8);
            const uint8_t* aq = ap + 32 * 520;
            uint64_t lo1 = *(const uint64_t*)aq;
            uint64_t hi1 = *(const uint64_t*)(aq + 8);
            v4i a0 = {(int)(uint32_t)lo0, (int)(lo0 >> 32),
                      (int)(uint32_t)hi0, (int)(hi0 >> 32)};
            v4i a1 = {(int)(uint32_t)lo1, (int)(lo1 >> 32),
                      (int)(uint32_t)hi1, (int)(hi1 >> 32)};
            acc0 = __builtin_amdgcn_mfma_i32_32x32x32_i8(a0, bf, acc0, 0, 0, 0);
            acc1 = __builtin_amdgcn_mfma_i32_32x32x32_i8(a1, bf, acc1, 0, 0, 0);
        }
        __syncthreads();
    }

    #pragma unroll
    for (int r = 0; r < 16; ++r) {
        int row0 = (r & 3) + 8 * (r >> 2);
        uint64_t mk0 = __ballot(acc0[r] >= T);
        uint64_t mk1 = __ballot(acc1[r] >= T);
        if (lane == 0) {
            h3w[(size_t)(s0 + row0) * 16 + jt]          = (uint32_t)mk0;
            h3w[(size_t)(s0 + row0 + 4) * 16 + jt]      = (uint32_t)(mk0 >> 32);
            h3w[(size_t)(s0 + 32 + row0) * 16 + jt]     = (uint32_t)mk1;
            h3w[(size_t)(s0 + 32 + row0 + 4) * 16 + jt] = (uint32_t)(mk1 >> 32);
        }
    }
}

// ---------------------------------------------------------------------------
// out kernel (unchanged)
// ---------------------------------------------------------------------------
__global__ __launch_bounds__(256) void out_kernel(
    const uint32_t* __restrict__ h3w,
    const uint32_t* __restrict__ wout,
    const float* __restrict__ out_b,
    float* __restrict__ out)
{
    int s = blockIdx.x * 256 + threadIdx.x;
    const uint4* hp = (const uint4*)(h3w + (size_t)s * 16);
    uint4 q0 = hp[0], q1 = hp[1], q2 = hp[2], q3 = hp[3];
    uint32_t w[16] = {q0.x, q0.y, q0.z, q0.w, q1.x, q1.y, q1.z, q1.w,
                      q2.x, q2.y, q2.z, q2.w, q3.x, q3.y, q3.z, q3.w};
    int B = 0;
    #pragma unroll
    for (int k = 0; k < 16; ++k) B += __popc(w[k]);
    #pragma unroll
    for (int o = 0; o < 10; ++o) {
        int P = 0;
        #pragma unroll
        for (int k = 0; k < 16; ++k) P += __popc(w[k] & wout[o * 16 + k]);
        out[(size_t)s * 10 + o] = __fadd_rn((float)(2 * P - B), out_b[o]);
    }
}

// ---------------------------------------------------------------------------
extern "C" void kernel_launch(void* const* d_in, const int* in_sizes, int n_in,
                              void* d_out, int out_size, void* d_ws, size_t ws_size,
                              hipStream_t stream)
{
    const float* x       = (const float*)d_in[0];
    const float* conv1_w = (const float*)d_in[1];
    const float* conv1_b = (const float*)d_in[2];
    const float* bn1_g   = (const float*)d_in[3];
    const float* bn1_b   = (const float*)d_in[4];
    const float* bn1_m   = (const float*)d_in[5];
    const float* bn1_v   = (const float*)d_in[6];
    const float* conv2_w = (const float*)d_in[7];
    const float* conv2_b = (const float*)d_in[8];
    const float* bn2_g   = (const float*)d_in[9];
    const float* bn2_b   = (const float*)d_in[10];
    const float* bn2_m   = (const float*)d_in[11];
    const float* bn2_v   = (const float*)d_in[12];
    const float* lin_w   = (const float*)d_in[13];
    const float* lin_b   = (const float*)d_in[14];
    const float* out_w   = (const float*)d_in[15];
    const float* out_b   = (const float*)d_in[16];

    char* ws = (char*)d_ws;
    uint32_t* h2b    = (uint32_t*)(ws + 0);
    uint4*    wbfrag = (uint4*)   (ws + 4194304);
    uint32_t* h3w    = (uint32_t*)(ws + 6291456);
    uint32_t* cdat   = (uint32_t*)(ws + 6815744);
    uint32_t* lut    = (uint32_t*)(ws + 6818304);
    uint32_t* wout   = (uint32_t*)(ws + 6820352);
    int*      Tlin   = (int*)     (ws + 6820992);
    uint4*    wcfrag = (uint4*)   (ws + 6855808);

    pack_kernel<<<525, 256, 0, stream>>>(conv1_w, conv1_b, conv2_w, conv2_b,
                                         lin_w, lin_b, out_w,
                                         bn1_g, bn1_b, bn1_m, bn1_v,
                                         bn2_g, bn2_b, bn2_m, bn2_v,
                                         wbfrag, cdat, lut, wout, Tlin, wcfrag);
    conv_kernel<<<NB / 4, 256, 0, stream>>>(x, cdat, lut, wcfrag, h2b);
    lin2_kernel<<<512, 256, 0, stream>>>(h2b, wbfrag, Tlin, h3w);
    out_kernel<<<32, 256, 0, stream>>>(h3w, wout, out_b, (float*)d_out);
}

// Round 3
// 170.684 us; speedup vs baseline: 1.1111x; 1.0270x over previous
//
#include <hip/hip_runtime.h>
#include <cstdint>

#define BN_EPS 1e-5f

static constexpr int NB = 8192;
static constexpr int JLIN = 500;

typedef int v4i  __attribute__((ext_vector_type(4)));
typedef int v16i __attribute__((ext_vector_type(16)));

// ---------------------------------------------------------------------------
// ws layout
//  h2b    [8192][128] u32      @ 0         4 MB  (bit-packed, row-major/sample)
//  wbfrag [16][128][64] uint4  @ 4194304   2 MB  (lin B frags, lane order)
//  h3w    [8192][16] u32       @ 6291456   512 KB
//  cdat   [640] u32            @ 6815744   (thresholds at [576..639]; masks legacy)
//  lut    [512] u32            @ 6818304
//  wout   [160] u32            @ 6820352
//  Tlin   [512] i32            @ 6820992
//  (gap: Bs legacy)            @ 6823040
//  wcfrag [9][2][64] uint4     @ 6855808   18 KB (conv2 B frags, lane order)
// ---------------------------------------------------------------------------

// ---------------------------------------------------------------------------
// pack kernel, grid = 525 blocks (unchanged)
// ---------------------------------------------------------------------------
__global__ __launch_bounds__(256) void pack_kernel(
    const float* __restrict__ conv1_w, const float* __restrict__ conv1_b,
    const float* __restrict__ conv2_w, const float* __restrict__ conv2_b,
    const float* __restrict__ lin_w, const float* __restrict__ lin_b,
    const float* __restrict__ out_w,
    const float* __restrict__ bn1_g, const float* __restrict__ bn1_b,
    const float* __restrict__ bn1_m, const float* __restrict__ bn1_v,
    const float* __restrict__ bn2_g, const float* __restrict__ bn2_b,
    const float* __restrict__ bn2_m, const float* __restrict__ bn2_v,
    uint4* __restrict__ wbfrag, uint32_t* __restrict__ cdat,
    uint32_t* __restrict__ lut, uint32_t* __restrict__ wout,
    int* __restrict__ Tlin, uint4* __restrict__ wcfrag)
{
    __shared__ float    s_c1w[288];
    __shared__ uint32_t s_wp[32];
    __shared__ float    s_inv1[32], s_sh1[32], s_b1[32];

    int tid = threadIdx.x;
    int b   = blockIdx.x;

    if (b < 512) {
        // ---- lin B fragment: jt, kq, lane; 16 i8 ----
        int e  = b * 256 + tid;
        int L  = e & 63;
        int kq = (e >> 6) & 127;
        int jt = e >> 13;
        int j  = jt * 32 + (L & 31);
        int h  = L >> 5;
        uint32_t dd[4] = {0u, 0u, 0u, 0u};
        if (j < JLIN) {
            int c  = kq >> 1, hi = kq & 1;
            int nb = (hi ? 28 : 32) - 16 * h;
            const float* src = lin_w + (size_t)j * 3840 + c * 60 + hi * 32 + 16 * h;
            #pragma unroll
            for (int i = 0; i < 16; ++i) {
                uint32_t byte = 0;
                if (i < nb) byte = (src[i] > 0.0f) ? 0x01u : 0xFFu;
                dd[i >> 2] |= byte << (8 * (i & 3));
            }
        }
        wbfrag[e] = make_uint4(dd[0], dd[1], dd[2], dd[3]);
        return;
    }

    if (b >= 520) {
        // ---- conv2 B fragment: idx = t*128 + n*64 + L ----
        int e = (b - 520) * 256 + tid;      // 0..1279, use <1152
        if (e < 1152) {
            int t = e >> 7;                 // tap 0..8 (ky*3+kx)
            int n = (e >> 6) & 1;
            int L = e & 63;
            int c = n * 32 + (L & 31);
            int hb = L >> 5;
            bool flip = (bn2_g[c] < 0.0f);  // sign(inv) = sign(gamma)
            uint32_t dd[4] = {0u, 0u, 0u, 0u};
            #pragma unroll
            for (int i = 0; i < 16; ++i) {
                int ic = 16 * hb + i;
                float w = conv2_w[c * 288 + ic * 9 + t];
                uint32_t byte = ((w > 0.0f) == flip) ? 0xFFu : 0x01u;  // -1 / +1
                dd[i >> 2] |= byte << (8 * (i & 3));
            }
            wcfrag[e] = make_uint4(dd[0], dd[1], dd[2], dd[3]);
        }
        return;
    }

    int mb = b - 512;
    if (mb < 2) {
        // ---- conv1 LUT ----
        for (int i = tid; i < 288; i += 256) s_c1w[i] = conv1_w[i];
        __syncthreads();
        if (tid < 32) {
            uint32_t wp = 0;
            for (int t = 0; t < 9; ++t)
                wp |= (s_c1w[tid * 9 + t] < 0.0f ? 1u : 0u) << t;
            s_wp[tid] = wp;
            float inv = bn1_g[tid] / sqrtf(bn1_v[tid] + BN_EPS);
            s_inv1[tid] = inv;
            s_sh1[tid]  = bn1_b[tid] - bn1_m[tid] * inv;
            s_b1[tid]   = conv1_b[tid];
        }
        __syncthreads();
        uint32_t px = (uint32_t)(mb * 256 + tid);
        uint32_t word = 0;
        for (int c = 0; c < 32; ++c) {
            int d = 9 - 2 * __popc(px ^ s_wp[c]);
            float z = __fadd_rn((float)d, s_b1[c]);
            z = __fadd_rn(__fmul_rn(z, s_inv1[c]), s_sh1[c]);
            word |= (z > 0.0f ? 1u : 0u) << c;
        }
        lut[px] = word;
        return;
    }

    int idx = (mb - 2) * 256 + tid;     // 0..1535
    if (idx < 576) {
        // legacy masks (unused by MFMA conv; cheap, kept)
        int c = idx / 9, tap = idx % 9;
        uint32_t w = 0;
        for (int ic = 0; ic < 32; ++ic)
            w |= (conv2_w[c * 288 + ic * 9 + tap] > 0.0f ? 1u : 0u) << ic;
        float inv = bn2_g[c] / sqrtf(bn2_v[c] + BN_EPS);
        if (inv < 0.0f) w = ~w;
        cdat[tap * 64 + c] = w;
    } else if (idx < 576 + 64) {
        // conv2 integer thresholds on D = chsign * conv (exact monotone scan)
        int c = idx - 576;
        float inv = bn2_g[c] / sqrtf(bn2_v[c] + BN_EPS);
        float sh  = bn2_b[c] - bn2_m[c] * inv;
        float b2  = conv2_b[c];
        int T = 10000;
        for (int u = -300; u <= 300; ++u) {
            float v = (inv < 0.0f) ? (float)(-u) : (float)u;
            float z = __fadd_rn(__fmul_rn(__fadd_rn(v, b2), inv), sh);
            if (z > 0.0f) { T = u; break; }
        }
        cdat[576 + c] = (uint32_t)T;
    } else if (idx < 576 + 64 + 512) {
        int j = idx - (576 + 64);
        int T = 10000;
        if (j < JLIN) {
            float lb = lin_b[j];
            int base = (int)floorf(-lb) - 2;
            for (int u = base; u <= base + 5; ++u)
                if (__fadd_rn((float)u, lb) > 0.0f) { T = u; break; }
        }
        Tlin[j] = T;
    } else if (idx < 576 + 64 + 512 + 160) {
        int t = idx - (576 + 64 + 512);
        int j = t >> 4, k = t & 15;
        uint32_t w = 0;
        for (int bb = 0; bb < 32; ++bb) {
            int jj = k * 32 + bb;
            if (jj < JLIN) w |= (out_w[j * 500 + jj] > 0.0f ? 1u : 0u) << bb;
        }
        wout[t] = w;
    }
}

// ---------------------------------------------------------------------------
// conv kernel (unchanged from R2): ONE WAVE = ONE SAMPLE, no inter-wave deps.
// ---------------------------------------------------------------------------
__global__ __launch_bounds__(256) void conv_kernel(
    const float* __restrict__ x,
    const uint32_t* __restrict__ cdat,
    const uint32_t* __restrict__ lut,
    const uint4* __restrict__ wcfrag,
    uint32_t* __restrict__ h2b)
{
    __shared__ uint32_t s_lut[512];
    __shared__ __align__(8) uint32_t s_flat[4][44];   // per-wave sign bitmap
    __shared__ uint32_t s_words[4][288];              // per-wave conv1 words
    __shared__ uint64_t s_bal[4][2][2][16];           // per-wave ballots

    int tid  = threadIdx.x;
    int lane = tid & 63;
    int wv   = tid >> 6;
    int s    = blockIdx.x * 4 + wv;

    s_lut[tid]       = lut[tid];
    s_lut[tid + 256] = lut[tid + 256];
    __syncthreads();

    // ---- ph1: sign bitmap ----
    const float* xs = x + (size_t)s * 1296;
    float xv[21];
    #pragma unroll
    for (int it = 0; it < 21; ++it) {
        int f = it * 64 + lane;
        xv[it] = (f < 1296) ? xs[f] : 1.0f;
    }
    #pragma unroll
    for (int it = 0; it < 21; ++it) {
        uint64_t mk = __ballot(xv[it] < 0.0f);
        if (lane == 0) *(uint64_t*)&s_flat[wv][2 * it] = mk;
    }
    asm volatile("s_waitcnt lgkmcnt(0)" ::: "memory");
    __builtin_amdgcn_sched_barrier(0);

    // ---- ph2: conv1 via LUT -> per-wave word table ----
    #pragma unroll
    for (int ii = 0; ii < 5; ++ii) {
        int wnd = ii * 64 + lane;
        if (wnd < 286) {
            int oy = wnd / 26, ox = wnd - 26 * oy;
            uint32_t pxb = 0;
            #pragma unroll
            for (int ky = 0; ky < 3; ++ky) {
                int bitpos = 54 * (2 * oy + ky) + 2 * ox;
                int d = bitpos >> 5, sh = bitpos & 31;
                uint64_t wp = (uint64_t)s_flat[wv][d] |
                              ((uint64_t)s_flat[wv][d + 1] << 32);
                pxb |= (((uint32_t)(wp >> sh)) & 7u) << (3 * ky);
            }
            s_words[wv][wnd] = s_lut[pxb];
        }
    }
    asm volatile("s_waitcnt lgkmcnt(0)" ::: "memory");
    __builtin_amdgcn_sched_barrier(0);

    // ---- phM: 2 row-tiles x 2 ch-tiles, 9 accumulating taps ----
    int row32 = lane & 31;
    int hb    = lane >> 5;
    int sh_hb = 16 * hb;
    int p1v   = 32 + row32; if (p1v > 59) p1v = 59;
    int wb0, wb1;
    { int oy = row32 / 12, ox = row32 - 12 * oy; wb0 = 52 * oy + 2 * ox; }
    { int oy = p1v / 12,   ox = p1v - 12 * oy;   wb1 = 52 * oy + 2 * ox; }

    v16i acc[2][2] = {};
    #pragma unroll
    for (int t = 0; t < 9; ++t) {
        const int koff = (t / 3) * 26 + (t % 3);
        uint4 b0 = wcfrag[t * 128 + lane];
        uint4 b1 = wcfrag[t * 128 + 64 + lane];
        v4i bf0 = {(int)b0.x, (int)b0.y, (int)b0.z, (int)b0.w};
        v4i bf1 = {(int)b1.x, (int)b1.y, (int)b1.z, (int)b1.w};
        #pragma unroll
        for (int rt = 0; rt < 2; ++rt) {
            uint32_t w  = s_words[wv][(rt ? wb1 : wb0) + koff];
            uint32_t hw = w >> sh_hb;
            v4i af;
            af[0] = (int)((((hw      ) & 0xFu) * 0x204081u) & 0x01010101u);
            af[1] = (int)((((hw >> 4 ) & 0xFu) * 0x204081u) & 0x01010101u);
            af[2] = (int)((((hw >> 8 ) & 0xFu) * 0x204081u) & 0x01010101u);
            af[3] = (int)((((hw >> 12) & 0xFu) * 0x204081u) & 0x01010101u);
            acc[rt][0] = __builtin_amdgcn_mfma_i32_32x32x32_i8(af, bf0, acc[rt][0], 0, 0, 0);
            acc[rt][1] = __builtin_amdgcn_mfma_i32_32x32x32_i8(af, bf1, acc[rt][1], 0, 0, 0);
        }
    }

    // ---- ballots: threshold per channel, write per-wave transpose buffer ----
    int T0 = (int)cdat[576 + row32];
    int T1 = (int)cdat[576 + 32 + row32];
    #pragma unroll
    for (int rt = 0; rt < 2; ++rt) {
        #pragma unroll
        for (int r = 0; r < 16; ++r) {
            uint64_t m0 = __ballot(acc[rt][0][r] >= T0);
            uint64_t m1 = __ballot(acc[rt][1][r] >= T1);
            if (lane == 0) {
                s_bal[wv][rt][0][r] = m0;
                s_bal[wv][rt][1][r] = m1;
            }
        }
    }
    asm volatile("s_waitcnt lgkmcnt(0)" ::: "memory");
    __builtin_amdgcn_sched_barrier(0);

    // ---- epi: each lane = one channel, assemble 60-bit word ----
    {
        int n  = lane >> 5, cc = lane & 31;
        uint32_t w0 = 0, w1 = 0;
        #pragma unroll
        for (int rt = 0; rt < 2; ++rt) {
            #pragma unroll
            for (int r = 0; r < 16; ++r) {
                const int base = (r & 3) + 8 * (r >> 2);      // 0..27
                uint64_t m = s_bal[wv][rt][n][r];
                uint32_t b0 = (uint32_t)(m >> cc) & 1u;
                uint32_t b1 = (uint32_t)(m >> (cc + 32)) & 1u;
                const int p0 = rt * 32 + base;
                const int p1 = p0 + 4;
                if (p0 < 32) w0 |= b0 << p0; else w1 |= b0 << (p0 - 32);
                if (p1 < 60) {
                    if (p1 < 32) w0 |= b1 << p1; else w1 |= b1 << (p1 - 32);
                }
            }
        }
        *(uint2*)(h2b + (size_t)s * 128 + 2 * lane) = make_uint2(w0, w1);
    }
}

// ---------------------------------------------------------------------------
// lin2 v2: 32-sample blocks for occupancy.
//  grid = 1024 (256 sblk x 4 jgrp), 4 waves/block, 1 jt per wave.
//  As = 32x520 B = 16.6 KB (was 33.3) -> 4 blocks/CU resident (was 2),
//  acc halves to one v16i (~60 VGPR). Same total MFMA/staging/HBM work,
//  2x the waves/CU to hide wbfrag L2 latency and barrier drains.
// ---------------------------------------------------------------------------
__global__ __launch_bounds__(256) void lin2_kernel(
    const uint32_t* __restrict__ h2b,
    const uint4* __restrict__ wbfrag,
    const int* __restrict__ Tlin,
    uint32_t* __restrict__ h3w)
{
    __shared__ uint8_t As[32 * 520];     // 16,640 B

    int tid  = threadIdx.x;
    int lane = tid & 63;
    int wv   = __builtin_amdgcn_readfirstlane((int)(tid >> 6));
    int sblk = blockIdx.x >> 2;
    int jgrp = blockIdx.x & 3;
    int jt   = jgrp * 4 + wv;
    int s0   = sblk * 32;

    int T = Tlin[jt * 32 + (lane & 31)];
    int row  = lane & 31;
    int half = lane >> 5;

    v16i acc = {};

    for (int chunk = 0; chunk < 8; ++chunk) {
        #pragma unroll
        for (int ii = 0; ii < 2; ++ii) {
            int e = ii * 256 + tid;          // 0..511
            int sm = e >> 4, wl = e & 15;
            uint32_t w = h2b[(size_t)(s0 + sm) * 128 + chunk * 16 + wl];
            uint32_t dw[8];
            #pragma unroll
            for (int q = 0; q < 8; ++q)
                dw[q] = (((w >> (4 * q)) & 0xFu) * 0x204081u) & 0x01010101u;
            uint64_t* dst = (uint64_t*)(As + sm * 520 + wl * 32);
            dst[0] = (uint64_t)dw[0] | ((uint64_t)dw[1] << 32);
            dst[1] = (uint64_t)dw[2] | ((uint64_t)dw[3] << 32);
            dst[2] = (uint64_t)dw[4] | ((uint64_t)dw[5] << 32);
            dst[3] = (uint64_t)dw[6] | ((uint64_t)dw[7] << 32);
        }
        __syncthreads();

        const uint4* bsrc = wbfrag + ((size_t)jt * 128 + chunk * 16) * 64 + lane;
        #pragma unroll 4
        for (int kq = 0; kq < 16; ++kq) {
            uint4 bw = bsrc[kq * 64];
            v4i bf = {(int)bw.x, (int)bw.y, (int)bw.z, (int)bw.w};
            const uint8_t* ap = As + row * 520 + kq * 32 + half * 16;
            uint64_t lo0 = *(const uint64_t*)ap;
            uint64_t hi0 = *(const uint64_t*)(ap + 8);
            v4i a0 = {(int)(uint32_t)lo0, (int)(lo0 >> 32),
                      (int)(uint32_t)hi0, (int)(hi0 >> 32)};
            acc = __builtin_amdgcn_mfma_i32_32x32x32_i8(a0, bf, acc, 0, 0, 0);
        }
        __syncthreads();
    }

    #pragma unroll
    for (int r = 0; r < 16; ++r) {
        int row0 = (r & 3) + 8 * (r >> 2);
        uint64_t mk = __ballot(acc[r] >= T);
        if (lane == 0) {
            h3w[(size_t)(s0 + row0) * 16 + jt]     = (uint32_t)mk;
            h3w[(size_t)(s0 + row0 + 4) * 16 + jt] = (uint32_t)(mk >> 32);
        }
    }
}

// ---------------------------------------------------------------------------
// out kernel (unchanged)
// ---------------------------------------------------------------------------
__global__ __launch_bounds__(256) void out_kernel(
    const uint32_t* __restrict__ h3w,
    const uint32_t* __restrict__ wout,
    const float* __restrict__ out_b,
    float* __restrict__ out)
{
    int s = blockIdx.x * 256 + threadIdx.x;
    const uint4* hp = (const uint4*)(h3w + (size_t)s * 16);
    uint4 q0 = hp[0], q1 = hp[1], q2 = hp[2], q3 = hp[3];
    uint32_t w[16] = {q0.x, q0.y, q0.z, q0.w, q1.x, q1.y, q1.z, q1.w,
                      q2.x, q2.y, q2.z, q2.w, q3.x, q3.y, q3.z, q3.w};
    int B = 0;
    #pragma unroll
    for (int k = 0; k < 16; ++k) B += __popc(w[k]);
    #pragma unroll
    for (int o = 0; o < 10; ++o) {
        int P = 0;
        #pragma unroll
        for (int k = 0; k < 16; ++k) P += __popc(w[k] & wout[o * 16 + k]);
        out[(size_t)s * 10 + o] = __fadd_rn((float)(2 * P - B), out_b[o]);
    }
}

// ---------------------------------------------------------------------------
extern "C" void kernel_launch(void* const* d_in, const int* in_sizes, int n_in,
                              void* d_out, int out_size, void* d_ws, size_t ws_size,
                              hipStream_t stream)
{
    const float* x       = (const float*)d_in[0];
    const float* conv1_w = (const float*)d_in[1];
    const float* conv1_b = (const float*)d_in[2];
    const float* bn1_g   = (const float*)d_in[3];
    const float* bn1_b   = (const float*)d_in[4];
    const float* bn1_m   = (const float*)d_in[5];
    const float* bn1_v   = (const float*)d_in[6];
    const float* conv2_w = (const float*)d_in[7];
    const float* conv2_b = (const float*)d_in[8];
    const float* bn2_g   = (const float*)d_in[9];
    const float* bn2_b   = (const float*)d_in[10];
    const float* bn2_m   = (const float*)d_in[11];
    const float* bn2_v   = (const float*)d_in[12];
    const float* lin_w   = (const float*)d_in[13];
    const float* lin_b   = (const float*)d_in[14];
    const float* out_w   = (const float*)d_in[15];
    const float* out_b   = (const float*)d_in[16];

    char* ws = (char*)d_ws;
    uint32_t* h2b    = (uint32_t*)(ws + 0);
    uint4*    wbfrag = (uint4*)   (ws + 4194304);
    uint32_t* h3w    = (uint32_t*)(ws + 6291456);
    uint32_t* cdat   = (uint32_t*)(ws + 6815744);
    uint32_t* lut    = (uint32_t*)(ws + 6818304);
    uint32_t* wout   = (uint32_t*)(ws + 6820352);
    int*      Tlin   = (int*)     (ws + 6820992);
    uint4*    wcfrag = (uint4*)   (ws + 6855808);

    pack_kernel<<<525, 256, 0, stream>>>(conv1_w, conv1_b, conv2_w, conv2_b,
                                         lin_w, lin_b, out_w,
                                         bn1_g, bn1_b, bn1_m, bn1_v,
                                         bn2_g, bn2_b, bn2_m, bn2_v,
                                         wbfrag, cdat, lut, wout, Tlin, wcfrag);
    conv_kernel<<<NB / 4, 256, 0, stream>>>(x, cdat, lut, wcfrag, h2b);
    lin2_kernel<<<1024, 256, 0, stream>>>(h2b, wbfrag, Tlin, h3w);
    out_kernel<<<32, 256, 0, stream>>>(h3w, wout, out_b, (float*)d_out);
}

// Round 4
// 161.547 us; speedup vs baseline: 1.1740x; 1.0566x over previous
//
#include <hip/hip_runtime.h>
#include <cstdint>

#define BN_EPS 1e-5f

static constexpr int NB = 8192;
static constexpr int JLIN = 500;

typedef int v4i  __attribute__((ext_vector_type(4)));
typedef int v16i __attribute__((ext_vector_type(16)));

// ---------------------------------------------------------------------------
// ws layout
//  h2b    [8192][128] u32      @ 0         4 MB  (bit-packed, row-major/sample)
//  wbfrag [16][128][64] uint4  @ 4194304   2 MB  (lin B frags, lane order)
//  h3w    [8192][16] u32       @ 6291456   512 KB
//  cdat   [640] u32            @ 6815744   (thresholds at [576..639]; masks legacy)
//  lut    [512] u32            @ 6818304
//  wout   [160] u32            @ 6820352
//  Tlin   [512] i32            @ 6820992
//  (gap: Bs legacy)            @ 6823040
//  wcfrag [9][2][64] uint4     @ 6855808   18 KB (conv2 B frags, lane order)
// ---------------------------------------------------------------------------

// ---------------------------------------------------------------------------
// pack kernel, grid = 525 blocks (unchanged)
// ---------------------------------------------------------------------------
__global__ __launch_bounds__(256) void pack_kernel(
    const float* __restrict__ conv1_w, const float* __restrict__ conv1_b,
    const float* __restrict__ conv2_w, const float* __restrict__ conv2_b,
    const float* __restrict__ lin_w, const float* __restrict__ lin_b,
    const float* __restrict__ out_w,
    const float* __restrict__ bn1_g, const float* __restrict__ bn1_b,
    const float* __restrict__ bn1_m, const float* __restrict__ bn1_v,
    const float* __restrict__ bn2_g, const float* __restrict__ bn2_b,
    const float* __restrict__ bn2_m, const float* __restrict__ bn2_v,
    uint4* __restrict__ wbfrag, uint32_t* __restrict__ cdat,
    uint32_t* __restrict__ lut, uint32_t* __restrict__ wout,
    int* __restrict__ Tlin, uint4* __restrict__ wcfrag)
{
    __shared__ float    s_c1w[288];
    __shared__ uint32_t s_wp[32];
    __shared__ float    s_inv1[32], s_sh1[32], s_b1[32];

    int tid = threadIdx.x;
    int b   = blockIdx.x;

    if (b < 512) {
        // ---- lin B fragment: jt, kq, lane; 16 i8 ----
        int e  = b * 256 + tid;
        int L  = e & 63;
        int kq = (e >> 6) & 127;
        int jt = e >> 13;
        int j  = jt * 32 + (L & 31);
        int h  = L >> 5;
        uint32_t dd[4] = {0u, 0u, 0u, 0u};
        if (j < JLIN) {
            int c  = kq >> 1, hi = kq & 1;
            int nb = (hi ? 28 : 32) - 16 * h;
            const float* src = lin_w + (size_t)j * 3840 + c * 60 + hi * 32 + 16 * h;
            #pragma unroll
            for (int i = 0; i < 16; ++i) {
                uint32_t byte = 0;
                if (i < nb) byte = (src[i] > 0.0f) ? 0x01u : 0xFFu;
                dd[i >> 2] |= byte << (8 * (i & 3));
            }
        }
        wbfrag[e] = make_uint4(dd[0], dd[1], dd[2], dd[3]);
        return;
    }

    if (b >= 520) {
        // ---- conv2 B fragment: idx = t*128 + n*64 + L ----
        int e = (b - 520) * 256 + tid;      // 0..1279, use <1152
        if (e < 1152) {
            int t = e >> 7;                 // tap 0..8 (ky*3+kx)
            int n = (e >> 6) & 1;
            int L = e & 63;
            int c = n * 32 + (L & 31);
            int hb = L >> 5;
            bool flip = (bn2_g[c] < 0.0f);  // sign(inv) = sign(gamma)
            uint32_t dd[4] = {0u, 0u, 0u, 0u};
            #pragma unroll
            for (int i = 0; i < 16; ++i) {
                int ic = 16 * hb + i;
                float w = conv2_w[c * 288 + ic * 9 + t];
                uint32_t byte = ((w > 0.0f) == flip) ? 0xFFu : 0x01u;  // -1 / +1
                dd[i >> 2] |= byte << (8 * (i & 3));
            }
            wcfrag[e] = make_uint4(dd[0], dd[1], dd[2], dd[3]);
        }
        return;
    }

    int mb = b - 512;
    if (mb < 2) {
        // ---- conv1 LUT ----
        for (int i = tid; i < 288; i += 256) s_c1w[i] = conv1_w[i];
        __syncthreads();
        if (tid < 32) {
            uint32_t wp = 0;
            for (int t = 0; t < 9; ++t)
                wp |= (s_c1w[tid * 9 + t] < 0.0f ? 1u : 0u) << t;
            s_wp[tid] = wp;
            float inv = bn1_g[tid] / sqrtf(bn1_v[tid] + BN_EPS);
            s_inv1[tid] = inv;
            s_sh1[tid]  = bn1_b[tid] - bn1_m[tid] * inv;
            s_b1[tid]   = conv1_b[tid];
        }
        __syncthreads();
        uint32_t px = (uint32_t)(mb * 256 + tid);
        uint32_t word = 0;
        for (int c = 0; c < 32; ++c) {
            int d = 9 - 2 * __popc(px ^ s_wp[c]);
            float z = __fadd_rn((float)d, s_b1[c]);
            z = __fadd_rn(__fmul_rn(z, s_inv1[c]), s_sh1[c]);
            word |= (z > 0.0f ? 1u : 0u) << c;
        }
        lut[px] = word;
        return;
    }

    int idx = (mb - 2) * 256 + tid;     // 0..1535
    if (idx < 576) {
        // legacy masks (unused by MFMA conv; cheap, kept)
        int c = idx / 9, tap = idx % 9;
        uint32_t w = 0;
        for (int ic = 0; ic < 32; ++ic)
            w |= (conv2_w[c * 288 + ic * 9 + tap] > 0.0f ? 1u : 0u) << ic;
        float inv = bn2_g[c] / sqrtf(bn2_v[c] + BN_EPS);
        if (inv < 0.0f) w = ~w;
        cdat[tap * 64 + c] = w;
    } else if (idx < 576 + 64) {
        // conv2 integer thresholds on D = chsign * conv (exact monotone scan)
        int c = idx - 576;
        float inv = bn2_g[c] / sqrtf(bn2_v[c] + BN_EPS);
        float sh  = bn2_b[c] - bn2_m[c] * inv;
        float b2  = conv2_b[c];
        int T = 10000;
        for (int u = -300; u <= 300; ++u) {
            float v = (inv < 0.0f) ? (float)(-u) : (float)u;
            float z = __fadd_rn(__fmul_rn(__fadd_rn(v, b2), inv), sh);
            if (z > 0.0f) { T = u; break; }
        }
        cdat[576 + c] = (uint32_t)T;
    } else if (idx < 576 + 64 + 512) {
        int j = idx - (576 + 64);
        int T = 10000;
        if (j < JLIN) {
            float lb = lin_b[j];
            int base = (int)floorf(-lb) - 2;
            for (int u = base; u <= base + 5; ++u)
                if (__fadd_rn((float)u, lb) > 0.0f) { T = u; break; }
        }
        Tlin[j] = T;
    } else if (idx < 576 + 64 + 512 + 160) {
        int t = idx - (576 + 64 + 512);
        int j = t >> 4, k = t & 15;
        uint32_t w = 0;
        for (int bb = 0; bb < 32; ++bb) {
            int jj = k * 32 + bb;
            if (jj < JLIN) w |= (out_w[j * 500 + jj] > 0.0f ? 1u : 0u) << bb;
        }
        wout[t] = w;
    }
}

// ---------------------------------------------------------------------------
// conv kernel: ONE WAVE = ONE SAMPLE. R4 change: epilogue transpose done
// in-register via per-lane compares + one __shfl_xor(32) per rt-tile,
// exploiting the MFMA D-layout (channel c's bits live only in lanes
// c&31 and (c&31)+32). Removes s_bal, 64 ballots, one lgkm drain, and
// the 60-iteration word-assembly loop.
// ---------------------------------------------------------------------------
__global__ __launch_bounds__(256) void conv_kernel(
    const float* __restrict__ x,
    const uint32_t* __restrict__ cdat,
    const uint32_t* __restrict__ lut,
    const uint4* __restrict__ wcfrag,
    uint32_t* __restrict__ h2b)
{
    __shared__ uint32_t s_lut[512];
    __shared__ __align__(8) uint32_t s_flat[4][44];   // per-wave sign bitmap
    __shared__ uint32_t s_words[4][288];              // per-wave conv1 words

    int tid  = threadIdx.x;
    int lane = tid & 63;
    int wv   = tid >> 6;
    int s    = blockIdx.x * 4 + wv;

    s_lut[tid]       = lut[tid];
    s_lut[tid + 256] = lut[tid + 256];
    __syncthreads();

    // ---- ph1: sign bitmap ----
    const float* xs = x + (size_t)s * 1296;
    float xv[21];
    #pragma unroll
    for (int it = 0; it < 21; ++it) {
        int f = it * 64 + lane;
        xv[it] = (f < 1296) ? xs[f] : 1.0f;
    }
    #pragma unroll
    for (int it = 0; it < 21; ++it) {
        uint64_t mk = __ballot(xv[it] < 0.0f);
        if (lane == 0) *(uint64_t*)&s_flat[wv][2 * it] = mk;
    }
    asm volatile("s_waitcnt lgkmcnt(0)" ::: "memory");
    __builtin_amdgcn_sched_barrier(0);

    // ---- ph2: conv1 via LUT -> per-wave word table ----
    #pragma unroll
    for (int ii = 0; ii < 5; ++ii) {
        int wnd = ii * 64 + lane;
        if (wnd < 286) {
            int oy = wnd / 26, ox = wnd - 26 * oy;
            uint32_t pxb = 0;
            #pragma unroll
            for (int ky = 0; ky < 3; ++ky) {
                int bitpos = 54 * (2 * oy + ky) + 2 * ox;
                int d = bitpos >> 5, sh = bitpos & 31;
                uint64_t wp = (uint64_t)s_flat[wv][d] |
                              ((uint64_t)s_flat[wv][d + 1] << 32);
                pxb |= (((uint32_t)(wp >> sh)) & 7u) << (3 * ky);
            }
            s_words[wv][wnd] = s_lut[pxb];
        }
    }
    asm volatile("s_waitcnt lgkmcnt(0)" ::: "memory");
    __builtin_amdgcn_sched_barrier(0);

    // ---- phM: 2 row-tiles x 2 ch-tiles, 9 accumulating taps ----
    int row32 = lane & 31;
    int hb    = lane >> 5;
    int sh_hb = 16 * hb;
    int p1v   = 32 + row32; if (p1v > 59) p1v = 59;
    int wb0, wb1;
    { int oy = row32 / 12, ox = row32 - 12 * oy; wb0 = 52 * oy + 2 * ox; }
    { int oy = p1v / 12,   ox = p1v - 12 * oy;   wb1 = 52 * oy + 2 * ox; }

    v16i acc[2][2] = {};
    #pragma unroll
    for (int t = 0; t < 9; ++t) {
        const int koff = (t / 3) * 26 + (t % 3);
        uint4 b0 = wcfrag[t * 128 + lane];
        uint4 b1 = wcfrag[t * 128 + 64 + lane];
        v4i bf0 = {(int)b0.x, (int)b0.y, (int)b0.z, (int)b0.w};
        v4i bf1 = {(int)b1.x, (int)b1.y, (int)b1.z, (int)b1.w};
        #pragma unroll
        for (int rt = 0; rt < 2; ++rt) {
            uint32_t w  = s_words[wv][(rt ? wb1 : wb0) + koff];
            uint32_t hw = w >> sh_hb;
            v4i af;
            af[0] = (int)((((hw      ) & 0xFu) * 0x204081u) & 0x01010101u);
            af[1] = (int)((((hw >> 4 ) & 0xFu) * 0x204081u) & 0x01010101u);
            af[2] = (int)((((hw >> 8 ) & 0xFu) * 0x204081u) & 0x01010101u);
            af[3] = (int)((((hw >> 12) & 0xFu) * 0x204081u) & 0x01010101u);
            acc[rt][0] = __builtin_amdgcn_mfma_i32_32x32x32_i8(af, bf0, acc[rt][0], 0, 0, 0);
            acc[rt][1] = __builtin_amdgcn_mfma_i32_32x32x32_i8(af, bf1, acc[rt][1], 0, 0, 0);
        }
    }

    // ---- epi: in-register word assembly.
    //  D layout: lane (cc=lane&31, hb=lane>>5) holds, for channel cc (acc*[0])
    //  and channel 32+cc (acc*[1]), positions (r&3)+8*(r>>2)+4*hb of rt-tile.
    //  Merge the two half-position sets across the lane pair (L, L^32) with
    //  one shfl_xor per rt. Lane L stores channel L's uint2 word. ----
    {
        int T0 = (int)cdat[576 + row32];
        int T1 = (int)cdat[576 + 32 + row32];
        uint32_t w_rt[2];
        #pragma unroll
        for (int rt = 0; rt < 2; ++rt) {
            uint32_t lw0 = 0, lw1 = 0;
            #pragma unroll
            for (int r = 0; r < 16; ++r) {
                const uint32_t pb = 1u << ((r & 3) + 8 * (r >> 2));
                if (acc[rt][0][r] >= T0) lw0 |= pb;
                if (acc[rt][1][r] >= T1) lw1 |= pb;
            }
            lw0 <<= 4 * hb;                 // position offset for this half
            lw1 <<= 4 * hb;
            uint32_t send = hb ? lw0 : lw1; // what the partner lane needs
            uint32_t recv = (uint32_t)__shfl_xor((int)send, 32);
            w_rt[rt] = recv | (hb ? lw1 : lw0);
        }
        uint32_t w0 = w_rt[0];
        uint32_t w1 = w_rt[1] & 0x0FFFFFFFu;   // positions 32..59 only
        *(uint2*)(h2b + (size_t)s * 128 + 2 * lane) = make_uint2(w0, w1);
    }
}

// ---------------------------------------------------------------------------
// lin2 v3: 32-sample blocks + register prefetch of next chunk's h2b words
// (T14 issue-early/write-late split: loads issued right after the staging
// barrier, consumed next chunk -> latency hidden under 16 MFMAs).
// ---------------------------------------------------------------------------
__global__ __launch_bounds__(256) void lin2_kernel(
    const uint32_t* __restrict__ h2b,
    const uint4* __restrict__ wbfrag,
    const int* __restrict__ Tlin,
    uint32_t* __restrict__ h3w)
{
    __shared__ uint8_t As[32 * 520];     // 16,640 B

    int tid  = threadIdx.x;
    int lane = tid & 63;
    int wv   = __builtin_amdgcn_readfirstlane((int)(tid >> 6));
    int sblk = blockIdx.x >> 2;
    int jgrp = blockIdx.x & 3;
    int jt   = jgrp * 4 + wv;
    int s0   = sblk * 32;

    int T = Tlin[jt * 32 + (lane & 31)];
    int row  = lane & 31;
    int half = lane >> 5;

    // per-thread staging coordinates (fixed across chunks)
    int sm0 = tid >> 4,        wl0 = tid & 15;          // e = tid
    int sm1 = (256 + tid) >> 4, wl1 = tid & 15;         // e = 256+tid
    const uint32_t* src0 = h2b + (size_t)(s0 + sm0) * 128 + wl0;
    const uint32_t* src1 = h2b + (size_t)(s0 + sm1) * 128 + wl1;

    v16i acc = {};
    uint32_t wreg0 = src0[0];
    uint32_t wreg1 = src1[0];

    for (int chunk = 0; chunk < 8; ++chunk) {
        // write phase: expand prefetched words into As
        {
            uint32_t dw[8];
            #pragma unroll
            for (int q = 0; q < 8; ++q)
                dw[q] = (((wreg0 >> (4 * q)) & 0xFu) * 0x204081u) & 0x01010101u;
            uint64_t* dst = (uint64_t*)(As + sm0 * 520 + wl0 * 32);
            dst[0] = (uint64_t)dw[0] | ((uint64_t)dw[1] << 32);
            dst[1] = (uint64_t)dw[2] | ((uint64_t)dw[3] << 32);
            dst[2] = (uint64_t)dw[4] | ((uint64_t)dw[5] << 32);
            dst[3] = (uint64_t)dw[6] | ((uint64_t)dw[7] << 32);
            #pragma unroll
            for (int q = 0; q < 8; ++q)
                dw[q] = (((wreg1 >> (4 * q)) & 0xFu) * 0x204081u) & 0x01010101u;
            dst = (uint64_t*)(As + sm1 * 520 + wl1 * 32);
            dst[0] = (uint64_t)dw[0] | ((uint64_t)dw[1] << 32);
            dst[1] = (uint64_t)dw[2] | ((uint64_t)dw[3] << 32);
            dst[2] = (uint64_t)dw[4] | ((uint64_t)dw[5] << 32);
            dst[3] = (uint64_t)dw[6] | ((uint64_t)dw[7] << 32);
        }
        __syncthreads();

        // issue next chunk's loads (latency hides under the MFMA loop)
        if (chunk < 7) {
            wreg0 = src0[(chunk + 1) * 16];
            wreg1 = src1[(chunk + 1) * 16];
        }

        const uint4* bsrc = wbfrag + ((size_t)jt * 128 + chunk * 16) * 64 + lane;
        #pragma unroll 4
        for (int kq = 0; kq < 16; ++kq) {
            uint4 bw = bsrc[kq * 64];
            v4i bf = {(int)bw.x, (int)bw.y, (int)bw.z, (int)bw.w};
            const uint8_t* ap = As + row * 520 + kq * 32 + half * 16;
            uint64_t lo0 = *(const uint64_t*)ap;
            uint64_t hi0 = *(const uint64_t*)(ap + 8);
            v4i a0 = {(int)(uint32_t)lo0, (int)(lo0 >> 32),
                      (int)(uint32_t)hi0, (int)(hi0 >> 32)};
            acc = __builtin_amdgcn_mfma_i32_32x32x32_i8(a0, bf, acc, 0, 0, 0);
        }
        __syncthreads();
    }

    #pragma unroll
    for (int r = 0; r < 16; ++r) {
        int row0 = (r & 3) + 8 * (r >> 2);
        uint64_t mk = __ballot(acc[r] >= T);
        if (lane == 0) {
            h3w[(size_t)(s0 + row0) * 16 + jt]     = (uint32_t)mk;
            h3w[(size_t)(s0 + row0 + 4) * 16 + jt] = (uint32_t)(mk >> 32);
        }
    }
}

// ---------------------------------------------------------------------------
// out kernel (unchanged)
// ---------------------------------------------------------------------------
__global__ __launch_bounds__(256) void out_kernel(
    const uint32_t* __restrict__ h3w,
    const uint32_t* __restrict__ wout,
    const float* __restrict__ out_b,
    float* __restrict__ out)
{
    int s = blockIdx.x * 256 + threadIdx.x;
    const uint4* hp = (const uint4*)(h3w + (size_t)s * 16);
    uint4 q0 = hp[0], q1 = hp[1], q2 = hp[2], q3 = hp[3];
    uint32_t w[16] = {q0.x, q0.y, q0.z, q0.w, q1.x, q1.y, q1.z, q1.w,
                      q2.x, q2.y, q2.z, q2.w, q3.x, q3.y, q3.z, q3.w};
    int B = 0;
    #pragma unroll
    for (int k = 0; k < 16; ++k) B += __popc(w[k]);
    #pragma unroll
    for (int o = 0; o < 10; ++o) {
        int P = 0;
        #pragma unroll
        for (int k = 0; k < 16; ++k) P += __popc(w[k] & wout[o * 16 + k]);
        out[(size_t)s * 10 + o] = __fadd_rn((float)(2 * P - B), out_b[o]);
    }
}

// ---------------------------------------------------------------------------
extern "C" void kernel_launch(void* const* d_in, const int* in_sizes, int n_in,
                              void* d_out, int out_size, void* d_ws, size_t ws_size,
                              hipStream_t stream)
{
    const float* x       = (const float*)d_in[0];
    const float* conv1_w = (const float*)d_in[1];
    const float* conv1_b = (const float*)d_in[2];
    const float* bn1_g   = (const float*)d_in[3];
    const float* bn1_b   = (const float*)d_in[4];
    const float* bn1_m   = (const float*)d_in[5];
    const float* bn1_v   = (const float*)d_in[6];
    const float* conv2_w = (const float*)d_in[7];
    const float* conv2_b = (const float*)d_in[8];
    const float* bn2_g   = (const float*)d_in[9];
    const float* bn2_b   = (const float*)d_in[10];
    const float* bn2_m   = (const float*)d_in[11];
    const float* bn2_v   = (const float*)d_in[12];
    const float* lin_w   = (const float*)d_in[13];
    const float* lin_b   = (const float*)d_in[14];
    const float* out_w   = (const float*)d_in[15];
    const float* out_b   = (const float*)d_in[16];

    char* ws = (char*)d_ws;
    uint32_t* h2b    = (uint32_t*)(ws + 0);
    uint4*    wbfrag = (uint4*)   (ws + 4194304);
    uint32_t* h3w    = (uint32_t*)(ws + 6291456);
    uint32_t* cdat   = (uint32_t*)(ws + 6815744);
    uint32_t* lut    = (uint32_t*)(ws + 6818304);
    uint32_t* wout   = (uint32_t*)(ws + 6820352);
    int*      Tlin   = (int*)     (ws + 6820992);
    uint4*    wcfrag = (uint4*)   (ws + 6855808);

    pack_kernel<<<525, 256, 0, stream>>>(conv1_w, conv1_b, conv2_w, conv2_b,
                                         lin_w, lin_b, out_w,
                                         bn1_g, bn1_b, bn1_m, bn1_v,
                                         bn2_g, bn2_b, bn2_m, bn2_v,
                                         wbfrag, cdat, lut, wout, Tlin, wcfrag);
    conv_kernel<<<NB / 4, 256, 0, stream>>>(x, cdat, lut, wcfrag, h2b);
    lin2_kernel<<<1024, 256, 0, stream>>>(h2b, wbfrag, Tlin, h3w);
    out_kernel<<<32, 256, 0, stream>>>(h3w, wout, out_b, (float*)d_out);
}